// Round 2
// baseline (1341.347 us; speedup 1.0000x reference)
//
#include <hip/hip_runtime.h>
#include <hip/hip_bf16.h>
#include <cstdint>
#include <cstddef>

typedef __bf16 bf16_t;
typedef __bf16 bf16x8 __attribute__((ext_vector_type(8)));
typedef float  f32x4  __attribute__((ext_vector_type(4)));

#define NN 50000
#define NEDGE 800000
#define IND 256
#define HIDD 512
#define NLAYER 3
#define ODIM 256
#define THID 2048

// ---------- weight transpose + fp32->bf16 convert: Wt[n][k] = W[k][n] ----------
__global__ void k_transpose_w(const float* __restrict__ W, bf16_t* __restrict__ Wt,
                              int K, int N) {
  int idx = blockIdx.x * 256 + threadIdx.x;
  if (idx < K * N) {
    int k = idx / N, n = idx - k * N;
    Wt[(size_t)n * K + k] = (bf16_t)W[idx];
  }
}

// ---------- CSR build: histogram of dst ----------
__global__ void k_hist(const int* __restrict__ ei, int* __restrict__ cnt) {
  int e = blockIdx.x * 256 + threadIdx.x;
  if (e < NEDGE) atomicAdd(&cnt[ei[NEDGE + e]], 1);
}

// ---------- CSR build: exclusive scan (single block, 1024 threads) ----------
__global__ void k_scan(const int* __restrict__ cnt, int* __restrict__ off) {
  __shared__ int s[1024];
  __shared__ int carry;
  int tid = threadIdx.x;
  if (tid == 0) carry = 0;
  __syncthreads();
  for (int base = 0; base < NN; base += 1024) {
    int v = (base + tid < NN) ? cnt[base + tid] : 0;
    s[tid] = v;
    __syncthreads();
    for (int d = 1; d < 1024; d <<= 1) {
      int t = (tid >= d) ? s[tid - d] : 0;
      __syncthreads();
      s[tid] += t;
      __syncthreads();
    }
    if (base + tid < NN) off[base + tid] = s[tid] - v + carry;
    int tot = s[1023];
    __syncthreads();
    if (tid == 0) carry += tot;
    __syncthreads();
  }
  if (tid == 0) off[NN] = carry;
}

// ---------- CSR build: scatter src indices ----------
__global__ void k_scatter(const int* __restrict__ ei, const int* __restrict__ roff,
                          int* __restrict__ cur, int* __restrict__ csr) {
  int e = blockIdx.x * 256 + threadIdx.x;
  if (e < NEDGE) {
    int d = ei[NEDGE + e];
    int p = atomicAdd(&cur[d], 1);
    csr[roff[d] + p] = ei[e];
  }
}

// ---------- aggregation: z[n,:] = h[n,:] + sum_{src in CSR[n]} h[src,:] ----------
__global__ __launch_bounds__(256) void k_aggregate(
    const bf16_t* __restrict__ h,
    const int* __restrict__ roff, const int* __restrict__ csr,
    bf16_t* __restrict__ z) {
  int wid = blockIdx.x * 4 + (threadIdx.x >> 6);
  if (wid >= NN) return;
  int lane = threadIdx.x & 63;
  bf16x8 hv = *(const bf16x8*)(h + (size_t)wid * HIDD + lane * 8);
  float acc[8];
#pragma unroll
  for (int j = 0; j < 8; j++) acc[j] = (float)hv[j];
  int o0 = roff[wid], o1 = roff[wid + 1];
  for (int e = o0; e < o1; ++e) {
    int s = csr[e];
    bf16x8 v = *(const bf16x8*)(h + (size_t)s * HIDD + lane * 8);
#pragma unroll
    for (int j = 0; j < 8; j++) acc[j] += (float)v[j];
  }
  bf16x8 o;
#pragma unroll
  for (int j = 0; j < 8; j++) o[j] = (bf16_t)acc[j];
  *(bf16x8*)(z + (size_t)wid * HIDD + lane * 8) = o;
}

// ---------- bf16 MFMA GEMM ----------
// C[M,N] = act(A[M,K] * Bt[N,K]^T + bias[N])   (ACC: Cf += A*Bt^T, no bias)
// 128x128 tile, BK=64, 4 waves (2x2), wave=64x64 (4x4 frags of 16x16x32 MFMA).
// LDS XOR swizzle byte^=((row&7)<<4) kills ds_read_b128 bank conflicts.
template <int RELU, int AF32, int ACC>
__global__ __launch_bounds__(256) void k_gemm(
    const void* __restrict__ Av, int lda, int M,
    const bf16_t* __restrict__ Bt, int K,
    const float* __restrict__ bias,
    bf16_t* __restrict__ Cb, int ldcb,
    float* __restrict__ Cf, int ldcf) {
  __shared__ char smem[32768] __attribute__((aligned(16)));
  char* ldsA = smem;
  char* ldsB = smem + 16384;

  const int tid = threadIdx.x;
  const int lane = tid & 63;
  const int w = tid >> 6;
  const int wr = w >> 1, wc = w & 1;
  const int lrow = lane & 15, lk = lane >> 4;
  const int bm = blockIdx.x, bn = blockIdx.y;

  f32x4 acc[4][4];
#pragma unroll
  for (int m = 0; m < 4; m++)
#pragma unroll
    for (int n = 0; n < 4; n++) {
      acc[m][n][0] = 0.f; acc[m][n][1] = 0.f;
      acc[m][n][2] = 0.f; acc[m][n][3] = 0.f;
    }

  const int ktiles = K >> 6;
  for (int kt = 0; kt < ktiles; ++kt) {
    // ---- stage A[128][64] and Bt[128][64] into LDS (bf16, swizzled) ----
#pragma unroll
    for (int it = 0; it < 4; ++it) {
      int c = it * 256 + tid;       // 0..1023
      int row = c >> 3, k8 = c & 7; // 128 rows x 8 chunks of 8 elems
      int lo = (row * 128 + k8 * 16) ^ ((row & 7) << 4);
      int grow = bm * 128 + row;
      bf16x8 va;
#pragma unroll
      for (int j = 0; j < 8; j++) va[j] = (bf16_t)0.f;
      if (grow < M) {
        if (AF32) {
          const float* A = (const float*)Av;
          f32x4 u0 = *(const f32x4*)(A + (size_t)grow * lda + kt * 64 + k8 * 8);
          f32x4 u1 = *(const f32x4*)(A + (size_t)grow * lda + kt * 64 + k8 * 8 + 4);
#pragma unroll
          for (int j = 0; j < 4; j++) { va[j] = (bf16_t)u0[j]; va[4 + j] = (bf16_t)u1[j]; }
        } else {
          const bf16_t* A = (const bf16_t*)Av;
          va = *(const bf16x8*)(A + (size_t)grow * lda + kt * 64 + k8 * 8);
        }
      }
      *(bf16x8*)(ldsA + lo) = va;
      bf16x8 vb = *(const bf16x8*)(Bt + (size_t)(bn * 128 + row) * K + kt * 64 + k8 * 8);
      *(bf16x8*)(ldsB + lo) = vb;
    }
    __syncthreads();
    // ---- compute: 2 K-steps of 32, 16 MFMA each per wave ----
#pragma unroll
    for (int kk = 0; kk < 2; ++kk) {
      bf16x8 af[4], bfr[4];
#pragma unroll
      for (int m = 0; m < 4; m++) {
        int row = wr * 64 + m * 16 + lrow;
        af[m] = *(const bf16x8*)(ldsA + ((row * 128 + kk * 64 + lk * 16) ^ ((row & 7) << 4)));
      }
#pragma unroll
      for (int n = 0; n < 4; n++) {
        int col = wc * 64 + n * 16 + lrow;
        bfr[n] = *(const bf16x8*)(ldsB + ((col * 128 + kk * 64 + lk * 16) ^ ((col & 7) << 4)));
      }
#pragma unroll
      for (int m = 0; m < 4; m++)
#pragma unroll
        for (int n = 0; n < 4; n++)
          acc[m][n] = __builtin_amdgcn_mfma_f32_16x16x32_bf16(af[m], bfr[n], acc[m][n], 0, 0, 0);
    }
    __syncthreads();
  }

  // ---- epilogue: row=(lane>>4)*4+r (+16*m), col=lane&15 (+16*n) ----
#pragma unroll
  for (int m = 0; m < 4; m++) {
    int rb = bm * 128 + wr * 64 + m * 16 + lk * 4;
#pragma unroll
    for (int n = 0; n < 4; n++) {
      int col = bn * 128 + wc * 64 + n * 16 + lrow;
      float bv = ACC ? 0.f : bias[col];
#pragma unroll
      for (int r = 0; r < 4; r++) {
        int row = rb + r;
        if (row < M) {
          float v = acc[m][n][r] + bv;
          if (RELU) v = fmaxf(v, 0.f);
          if (Cb) Cb[(size_t)row * ldcb + col] = (bf16_t)v;
          if (Cf) {
            if (ACC) Cf[(size_t)row * ldcf + col] += v;
            else     Cf[(size_t)row * ldcf + col] = v;
          }
        }
      }
    }
  }
}

extern "C" void kernel_launch(void* const* d_in, const int* in_sizes, int n_in,
                              void* d_out, int out_size, void* d_ws, size_t ws_size,
                              hipStream_t stream) {
  const float* x    = (const float*)d_in[0];
  const int*   ei   = (const int*)d_in[1];   // [2][NEDGE]: src row, then dst row
  const float* in_W = (const float*)d_in[2];
  const float* in_b = (const float*)d_in[3];
  const float* cW1  = (const float*)d_in[4];
  const float* cb1  = (const float*)d_in[5];
  const float* cW2  = (const float*)d_in[6];
  const float* cb2  = (const float*)d_in[7];
  const float* oW   = (const float*)d_in[8];
  const float* ob   = (const float*)d_in[9];
  float* out = (float*)d_out;

  // ---- carve workspace (~162 MB total) ----
  char* ws = (char*)d_ws;
  size_t off = 0;
  auto alloc = [&](size_t bytes) -> char* {
    char* p = ws + off;
    off = (off + bytes + 255) & ~(size_t)255;
    return p;
  };
  bf16_t* h     = (bf16_t*)alloc((size_t)NN * HIDD * 2);           // 51.2 MB
  bf16_t* z1    = (bf16_t*)alloc((size_t)NN * HIDD * 2);           // 51.2 MB
  bf16_t* z2    = (bf16_t*)alloc((size_t)NN * HIDD * 2);           // 51.2 MB
  bf16_t* wt_in = (bf16_t*)alloc((size_t)IND * HIDD * 2);          // [512][256]
  bf16_t* wt_c1 = (bf16_t*)alloc((size_t)NLAYER * HIDD * HIDD * 2);
  bf16_t* wt_c2 = (bf16_t*)alloc((size_t)NLAYER * HIDD * HIDD * 2);
  bf16_t* wt_ol = (bf16_t*)alloc((size_t)4 * ODIM * HIDD * 2);     // 4x[256][512]
  int* cnt  = (int*)alloc((size_t)NN * 4);
  int* cur  = (int*)alloc((size_t)NN * 4);
  int* roff = (int*)alloc((size_t)(NN + 1) * 4);
  int* csr  = (int*)alloc((size_t)NEDGE * 4);

  hipMemsetAsync(cnt, 0, (size_t)NN * 4, stream);
  hipMemsetAsync(cur, 0, (size_t)NN * 4, stream);

  // ---- weight conversion/transpose ----
  k_transpose_w<<<(IND * HIDD + 255) / 256, 256, 0, stream>>>(in_W, wt_in, IND, HIDD);
  for (int l = 0; l < NLAYER; ++l) {
    k_transpose_w<<<(HIDD * HIDD + 255) / 256, 256, 0, stream>>>(
        cW1 + (size_t)l * HIDD * HIDD, wt_c1 + (size_t)l * HIDD * HIDD, HIDD, HIDD);
    k_transpose_w<<<(HIDD * HIDD + 255) / 256, 256, 0, stream>>>(
        cW2 + (size_t)l * HIDD * HIDD, wt_c2 + (size_t)l * HIDD * HIDD, HIDD, HIDD);
  }
  for (int l = 0; l < NLAYER + 1; ++l) {
    // out_W rows l*512..(l+1)*512 -> wt_ol[l] = [256][512]
    k_transpose_w<<<(HIDD * ODIM + 255) / 256, 256, 0, stream>>>(
        oW + (size_t)l * HIDD * ODIM, wt_ol + (size_t)l * ODIM * HIDD, HIDD, ODIM);
  }

  // ---- CSR build ----
  k_hist<<<(NEDGE + 255) / 256, 256, 0, stream>>>(ei, cnt);
  k_scan<<<1, 1024, 0, stream>>>(cnt, roff);
  k_scatter<<<(NEDGE + 255) / 256, 256, 0, stream>>>(ei, roff, cur, csr);

  dim3 gH((NN + 127) / 128, HIDD / 128);  // N=512
  dim3 gO((NN + 127) / 128, ODIM / 128);  // N=256

  // ---- h0 = x @ in_W + in_b (fp32 A path) ----
  k_gemm<0, 1, 0><<<gH, 256, 0, stream>>>(x, IND, NN, wt_in, IND, in_b,
                                          h, HIDD, nullptr, 0);
  // ---- out = h0 @ oW[0] + ob ----
  k_gemm<0, 0, 0><<<gO, 256, 0, stream>>>(h, HIDD, NN, wt_ol, HIDD, ob,
                                          nullptr, 0, out, ODIM);

  // ---- GIN layers ----
  for (int l = 0; l < NLAYER; ++l) {
    k_aggregate<<<(NN + 3) / 4, 256, 0, stream>>>(h, roff, csr, z1);
    k_gemm<1, 0, 0><<<gH, 256, 0, stream>>>(z1, HIDD, NN,
                                            wt_c1 + (size_t)l * HIDD * HIDD, HIDD,
                                            cb1 + (size_t)l * HIDD, z2, HIDD, nullptr, 0);
    k_gemm<0, 0, 0><<<gH, 256, 0, stream>>>(z2, HIDD, NN,
                                            wt_c2 + (size_t)l * HIDD * HIDD, HIDD,
                                            cb2 + (size_t)l * HIDD, h, HIDD, nullptr, 0);
    // out += h_{l+1} @ oW[l+1]
    k_gemm<0, 0, 1><<<gO, 256, 0, stream>>>(h, HIDD, NN,
                                            wt_ol + (size_t)(l + 1) * ODIM * HIDD, HIDD,
                                            nullptr, nullptr, 0, out, ODIM);
  }
}

// Round 3
// 1188.846 us; speedup vs baseline: 1.1283x; 1.1283x over previous
//
#include <hip/hip_runtime.h>
#include <hip/hip_bf16.h>
#include <cstdint>
#include <cstddef>

typedef __bf16 bf16_t;
typedef __bf16 bf16x8 __attribute__((ext_vector_type(8)));
typedef float  f32x4  __attribute__((ext_vector_type(4)));

#define NN 50000
#define NNPAD 50176   // 392*128, covers last GEMM tile's unguarded async reads
#define NEDGE 800000
#define IND 256
#define HIDD 512
#define NLAYER 3
#define ODIM 256

// async global->LDS, 16B per lane; LDS dest = wave-uniform base + lane*16
__device__ __forceinline__ void gload16(const void* g, void* l) {
  __builtin_amdgcn_global_load_lds((const __attribute__((address_space(1))) void*)g,
                                   (__attribute__((address_space(3))) void*)l, 16, 0, 0);
}

// ---------- LDS-tiled transpose + convert: Wt[n][k] = (bf16)W[k][n] ----------
__global__ __launch_bounds__(256) void k_transpose_w(const float* __restrict__ W,
                                                     bf16_t* __restrict__ Wt,
                                                     int K, int N) {
  __shared__ float t[32][33];
  int bx = blockIdx.x * 32;  // n base
  int by = blockIdx.y * 32;  // k base
  int tx = threadIdx.x & 31, ty = threadIdx.x >> 5;  // 32 x 8
#pragma unroll
  for (int i = 0; i < 32; i += 8) {
    int k = by + ty + i, n = bx + tx;
    t[ty + i][tx] = (k < K && n < N) ? W[(size_t)k * N + n] : 0.f;
  }
  __syncthreads();
#pragma unroll
  for (int i = 0; i < 32; i += 8) {
    int n = bx + ty + i, k = by + tx;
    if (n < N && k < K) Wt[(size_t)n * K + k] = (bf16_t)t[tx][ty + i];
  }
}

// ---------- CSR build ----------
__global__ void k_hist(const int* __restrict__ ei, int* __restrict__ cnt) {
  int e = blockIdx.x * 256 + threadIdx.x;
  if (e < NEDGE) atomicAdd(&cnt[ei[NEDGE + e]], 1);
}

// chunked exclusive scan, single block of 1024
__global__ __launch_bounds__(1024) void k_scan(const int* __restrict__ cnt,
                                               int* __restrict__ off) {
  __shared__ int s[1024];
  const int C = 49;  // ceil(50000/1024)
  int tid = threadIdx.x;
  int base = tid * C;
  int sum = 0;
  for (int i = 0; i < C; ++i) {
    int idx = base + i;
    if (idx < NN) sum += cnt[idx];
  }
  s[tid] = sum;
  __syncthreads();
  for (int d = 1; d < 1024; d <<= 1) {
    int t = (tid >= d) ? s[tid - d] : 0;
    __syncthreads();
    s[tid] += t;
    __syncthreads();
  }
  int prefix = s[tid] - sum;  // exclusive
  for (int i = 0; i < C; ++i) {
    int idx = base + i;
    if (idx < NN) {
      off[idx] = prefix;
      prefix += cnt[idx];
    }
  }
  if (tid == 1023) off[NN] = prefix;
}

__global__ void k_scatter(const int* __restrict__ ei, const int* __restrict__ roff,
                          int* __restrict__ cur, int* __restrict__ csr) {
  int e = blockIdx.x * 256 + threadIdx.x;
  if (e < NEDGE) {
    int d = ei[NEDGE + e];
    int p = atomicAdd(&cur[d], 1);
    csr[roff[d] + p] = ei[e];
  }
}

// ---------- aggregation: z[n,:] = h[n,:] + sum_{src in CSR[n]} h[src,:] ----------
// wave per node; 4-deep unrolled gather for MLP
__global__ __launch_bounds__(256) void k_aggregate(
    const bf16_t* __restrict__ h,
    const int* __restrict__ roff, const int* __restrict__ csr,
    bf16_t* __restrict__ z) {
  int wid = blockIdx.x * 4 + (threadIdx.x >> 6);
  if (wid >= NN) return;
  int lane = threadIdx.x & 63;
  const bf16_t* hp = h + lane * 8;
  bf16x8 hv = *(const bf16x8*)(hp + (size_t)wid * HIDD);
  float acc[8];
#pragma unroll
  for (int j = 0; j < 8; j++) acc[j] = (float)hv[j];
  int e = roff[wid], o1 = roff[wid + 1];
  for (; e + 4 <= o1; e += 4) {
    int s0 = csr[e], s1 = csr[e + 1], s2 = csr[e + 2], s3 = csr[e + 3];
    bf16x8 v0 = *(const bf16x8*)(hp + (size_t)s0 * HIDD);
    bf16x8 v1 = *(const bf16x8*)(hp + (size_t)s1 * HIDD);
    bf16x8 v2 = *(const bf16x8*)(hp + (size_t)s2 * HIDD);
    bf16x8 v3 = *(const bf16x8*)(hp + (size_t)s3 * HIDD);
#pragma unroll
    for (int j = 0; j < 8; j++)
      acc[j] += (float)v0[j] + (float)v1[j] + (float)v2[j] + (float)v3[j];
  }
  for (; e < o1; ++e) {
    int s = csr[e];
    bf16x8 v = *(const bf16x8*)(hp + (size_t)s * HIDD);
#pragma unroll
    for (int j = 0; j < 8; j++) acc[j] += (float)v[j];
  }
  bf16x8 o;
#pragma unroll
  for (int j = 0; j < 8; j++) o[j] = (bf16_t)acc[j];
  *(bf16x8*)(z + (size_t)wid * HIDD + lane * 8) = o;
}

// ---------- bf16 MFMA GEMM ----------
// C[M,N] = act(A[M,K] * Bt[N,K]^T + bias[N])   (ACC: Cf += A*Bt^T, no bias)
// 128x128 tile, BK=64, 4 waves (2x2). Staging via global_load_lds width=16:
// LDS dest linear, global source pre-swizzled (chunk j ^= row&7), swizzled ds_read.
// Bijective XCD blockIdx swizzle, bn-fastest within each XCD chunk (A-panel L2 reuse).
template <int RELU, int AF32, int ACC>
__global__ __launch_bounds__(256) void k_gemm(
    const void* __restrict__ Av, int lda, int M,
    const bf16_t* __restrict__ Bt, int K,
    const float* __restrict__ bias,
    bf16_t* __restrict__ Cb, int ldcb,
    float* __restrict__ Cf, int ldcf) {
  __shared__ char smem[32768] __attribute__((aligned(16)));
  char* ldsA = smem;
  char* ldsB = smem + 16384;

  const int tid = threadIdx.x;
  const int lane = tid & 63;
  const int w = tid >> 6;
  const int wr = w >> 1, wc = w & 1;
  const int lrow = lane & 15, lk = lane >> 4;

  // bijective XCD swizzle (m204): contiguous grid chunk per XCD, bn-fastest inside
  const int gN = gridDim.x;
  const int nwg = gN * gridDim.y;
  const int id = blockIdx.y * gN + blockIdx.x;
  const int q = nwg >> 3, r = nwg & 7;
  const int xcd = id & 7, loc = id >> 3;
  const int nid = (xcd < r ? xcd * (q + 1) : r * (q + 1) + (xcd - r) * q) + loc;
  const int bn = nid % gN;
  const int bm = nid / gN;

  f32x4 acc[4][4];
#pragma unroll
  for (int m = 0; m < 4; m++)
#pragma unroll
    for (int n = 0; n < 4; n++) {
      acc[m][n][0] = 0.f; acc[m][n][1] = 0.f;
      acc[m][n][2] = 0.f; acc[m][n][3] = 0.f;
    }

  // per-lane async-staging source: lane l -> row (l>>3), swizzled chunk (l&7)^(l>>3)
  const int srow = lane >> 3;
  const int sj = (lane & 7) ^ srow;
  const bf16_t* Abf = (const bf16_t*)Av;
  const bf16_t* srcA = Abf + (size_t)(bm * 128 + srow) * lda + sj * 8;
  const bf16_t* srcB = Bt + (size_t)(bn * 128 + srow) * K + sj * 8;

  const int ktiles = K >> 6;
  for (int kt = 0; kt < ktiles; ++kt) {
    // ---- B: always async 16B (4 instr/wave covers 128 rows x 64 k) ----
#pragma unroll
    for (int i = 0; i < 4; ++i) {
      int cb = i * 4 + w;
      gload16(srcB + (size_t)(cb * 8) * K + kt * 64, ldsB + cb * 1024);
    }
    if constexpr (AF32) {
      // ---- A: fp32 -> bf16 reg staging (guarded) ----
#pragma unroll
      for (int it = 0; it < 4; ++it) {
        int c = it * 256 + tid;
        int row = c >> 3, k8 = c & 7;
        int lo = (row * 128 + k8 * 16) ^ ((row & 7) << 4);
        int grow = bm * 128 + row;
        bf16x8 va;
#pragma unroll
        for (int j = 0; j < 8; j++) va[j] = (bf16_t)0.f;
        if (grow < M) {
          const float* A = (const float*)Av;
          f32x4 u0 = *(const f32x4*)(A + (size_t)grow * lda + kt * 64 + k8 * 8);
          f32x4 u1 = *(const f32x4*)(A + (size_t)grow * lda + kt * 64 + k8 * 8 + 4);
#pragma unroll
          for (int j = 0; j < 4; j++) { va[j] = (bf16_t)u0[j]; va[4 + j] = (bf16_t)u1[j]; }
        }
        *(bf16x8*)(ldsA + lo) = va;
      }
    } else {
      // ---- A: async 16B (rows beyond M read padded ws garbage; C rows guarded) ----
#pragma unroll
      for (int i = 0; i < 4; ++i) {
        int ca = i * 4 + w;
        gload16(srcA + (size_t)(ca * 8) * lda + kt * 64, ldsA + ca * 1024);
      }
    }
    __syncthreads();
    // ---- compute: 2 K-steps of 32, 16 MFMA each per wave ----
#pragma unroll
    for (int kk = 0; kk < 2; ++kk) {
      bf16x8 af[4], bfr[4];
#pragma unroll
      for (int m = 0; m < 4; m++) {
        int row = wr * 64 + m * 16 + lrow;
        af[m] = *(const bf16x8*)(ldsA + ((row * 128 + kk * 64 + lk * 16) ^ ((row & 7) << 4)));
      }
#pragma unroll
      for (int n = 0; n < 4; n++) {
        int col = wc * 64 + n * 16 + lrow;
        bfr[n] = *(const bf16x8*)(ldsB + ((col * 128 + kk * 64 + lk * 16) ^ ((col & 7) << 4)));
      }
#pragma unroll
      for (int m = 0; m < 4; m++)
#pragma unroll
        for (int n = 0; n < 4; n++)
          acc[m][n] = __builtin_amdgcn_mfma_f32_16x16x32_bf16(af[m], bfr[n], acc[m][n], 0, 0, 0);
    }
    __syncthreads();
  }

  // ---- epilogue: row=(lane>>4)*4+r (+16m), col=lane&15 (+16n) ----
#pragma unroll
  for (int m = 0; m < 4; m++) {
    int rb = bm * 128 + wr * 64 + m * 16 + lk * 4;
#pragma unroll
    for (int n = 0; n < 4; n++) {
      int col = bn * 128 + wc * 64 + n * 16 + lrow;
      float bv = ACC ? 0.f : bias[col];
#pragma unroll
      for (int r = 0; r < 4; r++) {
        int row = rb + r;
        if (row < M) {
          float v = acc[m][n][r] + bv;
          if (RELU) v = fmaxf(v, 0.f);
          if (Cb) Cb[(size_t)row * ldcb + col] = (bf16_t)v;
          if (Cf) {
            if (ACC) Cf[(size_t)row * ldcf + col] += v;
            else     Cf[(size_t)row * ldcf + col] = v;
          }
        }
      }
    }
  }
}

extern "C" void kernel_launch(void* const* d_in, const int* in_sizes, int n_in,
                              void* d_out, int out_size, void* d_ws, size_t ws_size,
                              hipStream_t stream) {
  const float* x    = (const float*)d_in[0];
  const int*   ei   = (const int*)d_in[1];   // [2][NEDGE]: src row, then dst row
  const float* in_W = (const float*)d_in[2];
  const float* in_b = (const float*)d_in[3];
  const float* cW1  = (const float*)d_in[4];
  const float* cb1  = (const float*)d_in[5];
  const float* cW2  = (const float*)d_in[6];
  const float* cb2  = (const float*)d_in[7];
  const float* oW   = (const float*)d_in[8];
  const float* ob   = (const float*)d_in[9];
  float* out = (float*)d_out;

  // ---- carve workspace (~163 MB) ----
  char* ws = (char*)d_ws;
  size_t off = 0;
  auto alloc = [&](size_t bytes) -> char* {
    char* p = ws + off;
    off = (off + bytes + 255) & ~(size_t)255;
    return p;
  };
  bf16_t* h     = (bf16_t*)alloc((size_t)NNPAD * HIDD * 2);
  bf16_t* z1    = (bf16_t*)alloc((size_t)NNPAD * HIDD * 2);
  bf16_t* z2    = (bf16_t*)alloc((size_t)NNPAD * HIDD * 2);
  bf16_t* wt_in = (bf16_t*)alloc((size_t)IND * HIDD * 2);
  bf16_t* wt_c1 = (bf16_t*)alloc((size_t)NLAYER * HIDD * HIDD * 2);
  bf16_t* wt_c2 = (bf16_t*)alloc((size_t)NLAYER * HIDD * HIDD * 2);
  bf16_t* wt_ol = (bf16_t*)alloc((size_t)4 * ODIM * HIDD * 2);
  int* cnt  = (int*)alloc((size_t)NN * 4);
  int* cur  = (int*)alloc((size_t)NN * 4);
  int* roff = (int*)alloc((size_t)(NN + 1) * 4);
  int* csr  = (int*)alloc((size_t)NEDGE * 4);

  hipMemsetAsync(cnt, 0, (size_t)NN * 4, stream);
  hipMemsetAsync(cur, 0, (size_t)NN * 4, stream);

  // ---- weight transpose/convert (LDS-tiled) ----
  auto txw = [&](const float* W, bf16_t* Wt, int K, int N) {
    dim3 g((N + 31) / 32, (K + 31) / 32);
    k_transpose_w<<<g, 256, 0, stream>>>(W, Wt, K, N);
  };
  txw(in_W, wt_in, IND, HIDD);
  for (int l = 0; l < NLAYER; ++l) {
    txw(cW1 + (size_t)l * HIDD * HIDD, wt_c1 + (size_t)l * HIDD * HIDD, HIDD, HIDD);
    txw(cW2 + (size_t)l * HIDD * HIDD, wt_c2 + (size_t)l * HIDD * HIDD, HIDD, HIDD);
  }
  for (int l = 0; l < NLAYER + 1; ++l)
    txw(oW + (size_t)l * HIDD * ODIM, wt_ol + (size_t)l * ODIM * HIDD, HIDD, ODIM);

  // ---- CSR build ----
  k_hist<<<(NEDGE + 255) / 256, 256, 0, stream>>>(ei, cnt);
  k_scan<<<1, 1024, 0, stream>>>(cnt, roff);
  k_scatter<<<(NEDGE + 255) / 256, 256, 0, stream>>>(ei, roff, cur, csr);

  dim3 gH(HIDD / 128, (NN + 127) / 128);  // (4, 391)
  dim3 gO(ODIM / 128, (NN + 127) / 128);  // (2, 391)

  // ---- h0 = x @ in_W + in_b (fp32 A path) ----
  k_gemm<0, 1, 0><<<gH, 256, 0, stream>>>(x, IND, NN, wt_in, IND, in_b,
                                          h, HIDD, nullptr, 0);
  // ---- out = h0 @ oW[0] + ob ----
  k_gemm<0, 0, 0><<<gO, 256, 0, stream>>>(h, HIDD, NN, wt_ol, HIDD, ob,
                                          nullptr, 0, out, ODIM);

  // ---- GIN layers ----
  for (int l = 0; l < NLAYER; ++l) {
    k_aggregate<<<(NN + 3) / 4, 256, 0, stream>>>(h, roff, csr, z1);
    k_gemm<1, 0, 0><<<gH, 256, 0, stream>>>(z1, HIDD, NN,
                                            wt_c1 + (size_t)l * HIDD * HIDD, HIDD,
                                            cb1 + (size_t)l * HIDD, z2, HIDD, nullptr, 0);
    k_gemm<0, 0, 0><<<gH, 256, 0, stream>>>(z2, HIDD, NN,
                                            wt_c2 + (size_t)l * HIDD * HIDD, HIDD,
                                            cb2 + (size_t)l * HIDD, h, HIDD, nullptr, 0);
    k_gemm<0, 0, 1><<<gO, 256, 0, stream>>>(h, HIDD, NN,
                                            wt_ol + (size_t)(l + 1) * ODIM * HIDD, HIDD,
                                            nullptr, nullptr, 0, out, ODIM);
  }
}